// Round 3
// baseline (433.303 us; speedup 1.0000x reference)
//
#include <hip/hip_runtime.h>

// out[b,n,m,f] = e0 + e1 * tanh((z - e2) * e3), params gathered per (b,f).
// B=16, N=8, M=1024, F=512. Memory-bound: 256 MiB in + 256 MiB out,
// floor ~85 us @ 6.29 TB/s (m13 copy ubench, identical 50/50 R/W pattern).
//
// MEASURED cache-policy matrix (timed-region overhead 292.6 us, calibrated r1):
//   NT load + NT store     : ~137 us, 3.9 TB/s   (r0/r2)
//   cached load + NT store : 163.5 us, 3.28 TB/s (r1, kernel counter row)
//   cached load + plain st : 6.29 TB/s           (m13 copy ubench)
//   any + plain store      : 6.5 TB/s            (harness fills, write-only)
// Every slow config has NT stores; every fast datapoint has plain stores.
// Hypothesis: NT stores force early eviction of dirty L2 lines -> small,
// poorly-batched HBM write bursts (DRAM row-hit loss, R/W turnaround).
// Plain stores let L2 accumulate and flush large sequential bursts.
// This revision: NT loads (keep: zero-reuse read stream must not evict the
// dirty store lines) + PLAIN stores (the single-variable change).
//
// tanh(x) = 1 - 2/(exp2(x*2/ln2)+1): branch-free, exact saturation.
// Per element: fma, exp2, add, rcp, fma -> ~70x slack vs HBM stream time.

typedef float vf4 __attribute__((ext_vector_type(4)));

__global__ __launch_bounds__(256, 4)
void TanhRT_45406394253467_kernel(const float* __restrict__ z,
                                  const int* __restrict__ mask,
                                  const float* __restrict__ eta,
                                  float* __restrict__ out) {
    const int tid   = threadIdx.x;       // 0..255
    const int fg    = tid & 127;         // f-group: f0 = fg*4 (covers F=512)
    const int rsub  = tid >> 7;          // 0 or 1: which of 2 rows per iter
    const int b     = blockIdx.y;        // 0..15
    const int chunk = blockIdx.x;        // 0..127, each chunk = 64 rows

    const int f0 = fg << 2;

    // Per-thread folded params, reused over all 64 rows this thread touches.
    //   arg2 = (z - e2)*e3*(2/ln2) = fma(z, A, B)
    //   out  = (e0+e1) + (-2*e1) * rcp(1 + exp2(arg2))
    const float C = 2.8853900817779268f;  // 2/ln(2)
    vf4 A, Bv, S, T;
    const int mbase = b * 512 + f0;
#pragma unroll
    for (int j = 0; j < 4; ++j) {
        const int m = mask[mbase + j];             // 0..12, L1/L2-hot (32 KiB)
        const float4 p = ((const float4*)eta)[m];  // {e0,e1,e2,e3}, 13x16B, L1-hot
        A[j] = p.w * C;
        Bv[j] = -(p.z * p.w * C);
        S[j] = p.x + p.y;
        T[j] = -2.0f * p.y;
    }

    // Row space: n*m = 8192 rows per b, each row 512 floats.
    // Block streams a contiguous 128 KiB region (64 rows); per iteration the
    // 4 waves cover 4 KiB contiguous (2 rows), stride 4 KiB between iters.
    const size_t row0 = (size_t)b * 8192 + (size_t)chunk * 64 + (size_t)rsub;
    const vf4* zp = (const vf4*)(z + row0 * 512 + f0);
    vf4*       op = (vf4*)(out + row0 * 512 + f0);

#pragma unroll 8
    for (int it = 0; it < 32; ++it) {
        const vf4 v = __builtin_nontemporal_load(zp + (size_t)it * 256);
        vf4 r;
        r.x = __builtin_fmaf(T.x, __builtin_amdgcn_rcpf(1.0f + __builtin_amdgcn_exp2f(__builtin_fmaf(v.x, A.x, Bv.x))), S.x);
        r.y = __builtin_fmaf(T.y, __builtin_amdgcn_rcpf(1.0f + __builtin_amdgcn_exp2f(__builtin_fmaf(v.y, A.y, Bv.y))), S.y);
        r.z = __builtin_fmaf(T.z, __builtin_amdgcn_rcpf(1.0f + __builtin_amdgcn_exp2f(__builtin_fmaf(v.z, A.z, Bv.z))), S.z);
        r.w = __builtin_fmaf(T.w, __builtin_amdgcn_rcpf(1.0f + __builtin_amdgcn_exp2f(__builtin_fmaf(v.w, A.w, Bv.w))), S.w);
        op[(size_t)it * 256] = r;   // PLAIN store (the single-variable change)
    }
}

extern "C" void kernel_launch(void* const* d_in, const int* in_sizes, int n_in,
                              void* d_out, int out_size, void* d_ws, size_t ws_size,
                              hipStream_t stream) {
    const float* z    = (const float*)d_in[0];
    const int*   mask = (const int*)d_in[1];
    const float* eta  = (const float*)d_in[2];
    float*       out  = (float*)d_out;

    dim3 grid(128, 16);   // 128 row-chunks x 16 batches
    dim3 block(256);
    TanhRT_45406394253467_kernel<<<grid, block, 0, stream>>>(z, mask, eta, out);
}

// Round 4
// 422.871 us; speedup vs baseline: 1.0247x; 1.0247x over previous
//
#include <hip/hip_runtime.h>

// out[b,n,m,f] = e0 + e1 * tanh((z - e2) * e3), params gathered per (b,f).
// B=16, N=8, M=1024, F=512. Memory-bound: 256 MiB in + 256 MiB out.
//
// MEASURED (r0-r3, timed-region overhead 292.6 us calibrated vs r1 counter row):
//   NT/NT   block-chunked : ~138 us, ~4.0 TB/s   (r0/r2, best)
//   NT/plain block-chunked: ~141 us              (r3 -> store policy is a null lever)
//   cached/NT block-chunked: 163.5 us, 3.28 TB/s (r1, direct)
//   m13 float4 copy (same 50/50 R/W mix):        6.29 TB/s
// Cache policy exhausted. Remaining structural difference vs a copy:
// chunked mapping = 2048 private 4-KiB windows at 128-KiB stride scattered
// over 512 MiB at every instant -> DRAM row-buffer thrash. A grid-stride
// copy walks ONE dense sliding front -> open-row reuse.
//
// THIS REVISION (single variable): batch-local grid-stride. blockIdx.y = b
// (param folding untouched; iteration stride 512 KiB == 0 mod 512 floats so
// per-thread f is invariant, f0 = (tid&127)*4 identical to before). Per
// iteration the 128 blocks of a batch cover one dense 512-KiB front; chip-wide
// 16 dense fronts instead of 2048 scattered windows. Everything else held:
// NT load + NT store, unroll 8, 16 B/lane, 1 KiB/wave contiguous.
//
// tanh(x) = 1 - 2/(exp2(x*2/ln2)+1): branch-free, exact saturation.
// Per element: fma, exp2, add, rcp, fma -> ~70x slack vs HBM stream time.

typedef float vf4 __attribute__((ext_vector_type(4)));

__global__ __launch_bounds__(256, 4)
void TanhRT_45406394253467_kernel(const float* __restrict__ z,
                                  const int* __restrict__ mask,
                                  const float* __restrict__ eta,
                                  float* __restrict__ out) {
    const int tid = threadIdx.x;         // 0..255
    const int b   = blockIdx.y;          // 0..15

    const int f0 = (tid & 127) << 2;     // per-thread f is iteration-invariant

    // Per-thread folded params, reused over all 32 iterations.
    //   arg2 = (z - e2)*e3*(2/ln2) = fma(z, A, B)
    //   out  = (e0+e1) + (-2*e1) * rcp(1 + exp2(arg2))
    const float C = 2.8853900817779268f;  // 2/ln(2)
    vf4 A, Bv, S, T;
    const int mbase = b * 512 + f0;
#pragma unroll
    for (int j = 0; j < 4; ++j) {
        const int m = mask[mbase + j];             // 0..12, L1/L2-hot
        const float4 p = ((const float4*)eta)[m];  // {e0,e1,e2,e3}, 13x16B, L1-hot
        A[j] = p.w * C;
        Bv[j] = -(p.z * p.w * C);
        S[j] = p.x + p.y;
        T[j] = -2.0f * p.y;
    }

    // Batch-local grid-stride: batch region = 16 MiB (4,194,304 floats).
    // Per iteration, blocks 0..127 of this batch cover a dense 512 KiB front
    // (128 blocks x 256 threads x 16 B); thread walks 32 fronts.
    const size_t base = (size_t)b * (8192 * 512)
                      + (size_t)blockIdx.x * 1024
                      + (size_t)tid * 4;
    const vf4* zp = (const vf4*)(z + base);
    vf4*       op = (vf4*)(out + base);

#pragma unroll 8
    for (int it = 0; it < 32; ++it) {
        const vf4 v = __builtin_nontemporal_load(zp + (size_t)it * 32768);
        vf4 r;
        r.x = __builtin_fmaf(T.x, __builtin_amdgcn_rcpf(1.0f + __builtin_amdgcn_exp2f(__builtin_fmaf(v.x, A.x, Bv.x))), S.x);
        r.y = __builtin_fmaf(T.y, __builtin_amdgcn_rcpf(1.0f + __builtin_amdgcn_exp2f(__builtin_fmaf(v.y, A.y, Bv.y))), S.y);
        r.z = __builtin_fmaf(T.z, __builtin_amdgcn_rcpf(1.0f + __builtin_amdgcn_exp2f(__builtin_fmaf(v.z, A.z, Bv.z))), S.z);
        r.w = __builtin_fmaf(T.w, __builtin_amdgcn_rcpf(1.0f + __builtin_amdgcn_exp2f(__builtin_fmaf(v.w, A.w, Bv.w))), S.w);
        __builtin_nontemporal_store(r, op + (size_t)it * 32768);
    }
}

extern "C" void kernel_launch(void* const* d_in, const int* in_sizes, int n_in,
                              void* d_out, int out_size, void* d_ws, size_t ws_size,
                              hipStream_t stream) {
    const float* z    = (const float*)d_in[0];
    const int*   mask = (const int*)d_in[1];
    const float* eta  = (const float*)d_in[2];
    float*       out  = (float*)d_out;

    dim3 grid(128, 16);   // 128 front-slices x 16 batches
    dim3 block(256);
    TanhRT_45406394253467_kernel<<<grid, block, 0, stream>>>(z, mask, eta, out);
}